// Round 3
// baseline (266.007 us; speedup 1.0000x reference)
//
#include <hip/hip_runtime.h>

// DotProductAttention (Swin windowed, masked softmax), n=1024, Q=K=256, d=32.
// Round 3 structure: compute S^T = K·Q^T so MFMA C-layout rows = k, cols = q.
//  - window-mask loads become vectorized b64 (4 contiguous k per lane)
//  - softmax k-reduction = per-lane + 2 cross-quad shuffles
//  - P transpose via PER-WAVE-PRIVATE LDS (no __syncthreads in main loop;
//    intra-wave ordering via in-order DS pipe + lgkmcnt fence)
//  - PV in two k-halves (halves P LDS) -> 34.3 KB LDS -> 4 blocks/CU
//  - O bounced through LDS -> fully coalesced dwordx4 stores
//  - XCD swizzle: 8 batches sharing one window mask land on the same XCD

typedef __attribute__((ext_vector_type(8))) short short8;   // 8 bf16 = 4 VGPR
typedef __attribute__((ext_vector_type(4))) float floatx4;  // MFMA C/D

#define VSTRIDE 264   // Vt row stride (ushorts): 256 + 8
#define PSTRIDE 136   // per-wave P (half-k) row stride: 128 + 8
#define OSTRIDE 40    // O bounce row stride
#define NEGV -1000000.0f

#define LDS_FENCE() __asm__ volatile("s_waitcnt lgkmcnt(0)" ::: "memory")

__device__ __forceinline__ float bf2f(unsigned short u) {
    union { unsigned u; float f; } x; x.u = ((unsigned)u) << 16;
    return x.f;
}
__device__ __forceinline__ float u2f_lo(unsigned u) {
    union { unsigned u; float f; } x; x.u = u << 16; return x.f;
}
__device__ __forceinline__ float u2f_hi(unsigned u) {
    union { unsigned u; float f; } x; x.u = u & 0xffff0000u; return x.f;
}
__device__ __forceinline__ unsigned short f2bf(float f) {
    union { float f; unsigned u; } x; x.f = f;
    unsigned r = (x.u + 0x7fffu + ((x.u >> 16) & 1u)) >> 16;  // RNE
    return (unsigned short)r;
}
__device__ __forceinline__ unsigned pack2bf(float a, float b) {
    return (unsigned)f2bf(a) | ((unsigned)f2bf(b) << 16);
}

// ---- runtime input-format detection (flags -> d_ws) ----
__global__ void detect_kernel(const unsigned short* __restrict__ Qg,
                              const int* __restrict__ VLg,
                              int* __restrict__ flags) {
    __shared__ int s_f32, s_vl64;
    const int tid = threadIdx.x;
    if (tid == 0) { s_f32 = 0; s_vl64 = 1; }
    __syncthreads();
    int f32_hit = 0;
    for (int i = tid; i < 4096; i += 256) {
        unsigned e = ((unsigned)Qg[i] >> 7) & 0xFFu;
        if (e >= 0xC0u) f32_hit = 1;
    }
    int odd_nonzero = 0;
    for (int i = tid; i < 1024; i += 256) {
        if ((i & 1) && VLg[i] != 0) odd_nonzero = 1;
    }
    if (f32_hit)     atomicOr(&s_f32, 1);
    if (odd_nonzero) atomicAnd(&s_vl64, 0);
    __syncthreads();
    if (tid == 0) { flags[0] = s_f32; flags[1] = s_vl64; }
}

template<bool F32>
__device__ __forceinline__ short8 load_frag8(const void* base, size_t elem_off) {
    if constexpr (!F32) {
        return *(const short8*)((const unsigned short*)base + elem_off);
    } else {
        const float* p = (const float*)base + elem_off;
        float4 a = *(const float4*)p;
        float4 b = *(const float4*)(p + 4);
        short8 r;
        r[0] = (short)f2bf(a.x); r[1] = (short)f2bf(a.y);
        r[2] = (short)f2bf(a.z); r[3] = (short)f2bf(a.w);
        r[4] = (short)f2bf(b.x); r[5] = (short)f2bf(b.y);
        r[6] = (short)f2bf(b.z); r[7] = (short)f2bf(b.w);
        return r;
    }
}

template<bool F32>
__global__ __launch_bounds__(256, 4)
void attn_swin_kernel(const void* __restrict__ Qv,
                      const void* __restrict__ Kv,
                      const void* __restrict__ Vv,
                      const int* __restrict__ VLg,
                      const void* __restrict__ Wv,
                      void* __restrict__ Ov,
                      const int* __restrict__ flags)
{
    const int is_f32 = flags[0];
    if ((is_f32 != 0) != F32) return;   // uniform early-exit
    const int vl64 = flags[1];

    __shared__ __align__(16) unsigned short Vt[32 * VSTRIDE];        // V^T: Vt[d][k]  (16.9 KB)
    __shared__ __align__(16) unsigned short Pq[4 * 16 * PSTRIDE];    // per-wave P^T (half-k) (17.4 KB)

    const int tid  = threadIdx.x;
    const int wave = tid >> 6;
    const int lane = tid & 63;
    const int c    = lane & 15;   // MFMA column (= q within group)
    const int quad = lane >> 4;   // 0..3

    // XCD swizzle: consecutive-blockIdx round-robin -> same-mask batches on one XCD
    const int blk = blockIdx.x;
    const int b   = (blk >> 3) + 128 * (blk & 7);

    int vl;
    if (vl64) vl = (int)(((const long long*)VLg)[b]);
    else      vl = VLg[b];
    vl = min(max(vl, 0), 256);

    const int used16 = (vl + 15) >> 4;   // active 16-wide k tiles
    const int used32 = (vl + 31) >> 5;   // active 32-wide k tiles (PV)
    const int tmax   = used32 * 2;       // P tiles that must exist (zeros past vl)
    const int w_idx  = (b >> 3) & 63;
    const size_t bbase = (size_t)b * 8192;

    // ---- stage V transposed into LDS: Vt[d][k] ----
    #pragma unroll
    for (int it = 0; it < 4; ++it) {
        const int d0 = it * 8;
        unsigned short tmp[8];
        if constexpr (!F32) {
            uint4 v = *(const uint4*)((const unsigned short*)Vv + bbase + (size_t)tid * 32 + d0);
            const unsigned short* pv = (const unsigned short*)&v;
            #pragma unroll
            for (int j = 0; j < 8; ++j) tmp[j] = pv[j];
        } else {
            const float* p = (const float*)Vv + bbase + (size_t)tid * 32 + d0;
            float4 a = *(const float4*)p;
            float4 d = *(const float4*)(p + 4);
            tmp[0] = f2bf(a.x); tmp[1] = f2bf(a.y); tmp[2] = f2bf(a.z); tmp[3] = f2bf(a.w);
            tmp[4] = f2bf(d.x); tmp[5] = f2bf(d.y); tmp[6] = f2bf(d.z); tmp[7] = f2bf(d.w);
        }
        #pragma unroll
        for (int j = 0; j < 8; ++j)
            Vt[(d0 + j) * VSTRIDE + tid] = tmp[j];
    }
    __syncthreads();   // only barrier in the kernel

    const float scale = 0.17677669529663687f;  // 1/sqrt(32)
    unsigned short* const pw = &Pq[wave * 16 * PSTRIDE];   // wave-private region

    for (int qt = 0; qt < 4; ++qt) {
        const int qbase = qt * 64 + wave * 16;

        // B-frag: this wave's 16 Q rows (B[k][n]: n=c, k=quad*8+j)
        short8 qb = load_frag8<F32>(Qv, bbase + (size_t)(qbase + c) * 32 + quad * 8);

        // ---- S^T tiles + vectorized mask loads ----
        floatx4 acc[16];
        uint2 mraw[16];
        const size_t wm_base = (size_t)w_idx * 65536 + (size_t)(qbase + c) * 256 + quad * 4;
        #pragma unroll
        for (int t = 0; t < 16; ++t) {
            if (t < used16) {
                // A-frag: K rows (A[m][k]: m=c -> k-row 16t+c, k=quad*8+j -> d)
                short8 ka = load_frag8<F32>(Kv, bbase + (size_t)(t * 16 + c) * 32 + quad * 8);
                floatx4 z = {0.f, 0.f, 0.f, 0.f};
                acc[t] = __builtin_amdgcn_mfma_f32_16x16x32_bf16(ka, qb, z, 0, 0, 0);
                if constexpr (!F32)
                    mraw[t] = *(const uint2*)((const unsigned short*)Wv + wm_base + t * 16);
            }
        }

        // ---- scale + mask + valid-len; per-lane max ----
        float mx = -3.0e38f;
        #pragma unroll
        for (int t = 0; t < 16; ++t) {
            if (t < used16) {
                float m0, m1, m2, m3;
                if constexpr (!F32) {
                    m0 = u2f_lo(mraw[t].x); m1 = u2f_hi(mraw[t].x);
                    m2 = u2f_lo(mraw[t].y); m3 = u2f_hi(mraw[t].y);
                } else {
                    const float* mp = (const float*)Wv + wm_base + t * 16;
                    m0 = mp[0]; m1 = mp[1]; m2 = mp[2]; m3 = mp[3];
                }
                float s0 = fmaf(acc[t][0], scale, m0);
                float s1 = fmaf(acc[t][1], scale, m1);
                float s2 = fmaf(acc[t][2], scale, m2);
                float s3 = fmaf(acc[t][3], scale, m3);
                if ((t + 1) * 16 > vl) {             // boundary tile: apply key mask
                    const int k0 = t * 16 + quad * 4;
                    s0 = (k0 + 0 < vl) ? s0 : NEGV;
                    s1 = (k0 + 1 < vl) ? s1 : NEGV;
                    s2 = (k0 + 2 < vl) ? s2 : NEGV;
                    s3 = (k0 + 3 < vl) ? s3 : NEGV;
                }
                acc[t][0] = s0; acc[t][1] = s1; acc[t][2] = s2; acc[t][3] = s3;
                mx = fmaxf(mx, fmaxf(fmaxf(s0, s1), fmaxf(s2, s3)));
            }
        }
        // reduce max across the 4 quads (lanes c, c+16, c+32, c+48)
        mx = fmaxf(mx, __shfl_xor(mx, 16));
        mx = fmaxf(mx, __shfl_xor(mx, 32));

        // ---- exp + sum; pack P to bf16 pairs ----
        float l = 0.f;
        uint2 pk[16];
        #pragma unroll
        for (int t = 0; t < 16; ++t) {
            if (t < used16) {
                float p0 = __expf(acc[t][0] - mx);
                float p1 = __expf(acc[t][1] - mx);
                float p2 = __expf(acc[t][2] - mx);
                float p3 = __expf(acc[t][3] - mx);
                l += (p0 + p1) + (p2 + p3);
                pk[t].x = pack2bf(p0, p1);
                pk[t].y = pack2bf(p2, p3);
            } else if (t < tmax) {
                pk[t].x = 0u; pk[t].y = 0u;
            }
        }
        l += __shfl_xor(l, 16);
        l += __shfl_xor(l, 32);
        const float rl = (l > 0.f) ? (1.0f / l) : 0.f;

        // ---- PV in two k-halves through wave-private LDS ----
        floatx4 o0 = {0.f, 0.f, 0.f, 0.f}, o1 = {0.f, 0.f, 0.f, 0.f};

        // half 0: k in [0,128)
        #pragma unroll
        for (int t = 0; t < 8; ++t) {
            if (t < tmax)
                *(uint2*)&pw[c * PSTRIDE + t * 16 + quad * 4] = pk[t];
        }
        LDS_FENCE();
        #pragma unroll
        for (int kt = 0; kt < 4; ++kt) {
            if (kt < used32) {
                short8 pb  = *(const short8*)&pw[c * PSTRIDE + kt * 32 + quad * 8];
                short8 va0 = *(const short8*)&Vt[c * VSTRIDE + kt * 32 + quad * 8];
                short8 va1 = *(const short8*)&Vt[(16 + c) * VSTRIDE + kt * 32 + quad * 8];
                o0 = __builtin_amdgcn_mfma_f32_16x16x32_bf16(va0, pb, o0, 0, 0, 0);
                o1 = __builtin_amdgcn_mfma_f32_16x16x32_bf16(va1, pb, o1, 0, 0, 0);
            }
        }
        // half 1: k in [128,256)  (in-order DS pipe makes WAR with half-0 reads safe)
        if (used32 > 4) {
            #pragma unroll
            for (int t = 8; t < 16; ++t) {
                if (t < tmax)
                    *(uint2*)&pw[c * PSTRIDE + (t - 8) * 16 + quad * 4] = pk[t];
            }
            LDS_FENCE();
            #pragma unroll
            for (int kt = 4; kt < 8; ++kt) {
                if (kt < used32) {
                    short8 pb  = *(const short8*)&pw[c * PSTRIDE + (kt - 4) * 32 + quad * 8];
                    short8 va0 = *(const short8*)&Vt[c * VSTRIDE + kt * 32 + quad * 8];
                    short8 va1 = *(const short8*)&Vt[(16 + c) * VSTRIDE + kt * 32 + quad * 8];
                    o0 = __builtin_amdgcn_mfma_f32_16x16x32_bf16(va0, pb, o0, 0, 0, 0);
                    o1 = __builtin_amdgcn_mfma_f32_16x16x32_bf16(va1, pb, o1, 0, 0, 0);
                }
            }
        }

        // ---- normalize; O^T C-layout -> coalesced store via LDS bounce ----
        if constexpr (!F32) {
            uint2 w0, w1;
            w0.x = pack2bf(o0[0] * rl, o0[1] * rl);
            w0.y = pack2bf(o0[2] * rl, o0[3] * rl);
            w1.x = pack2bf(o1[0] * rl, o1[1] * rl);
            w1.y = pack2bf(o1[2] * rl, o1[3] * rl);
            *(uint2*)&pw[c * OSTRIDE + quad * 4]      = w0;   // d = quad*4+r
            *(uint2*)&pw[c * OSTRIDE + 16 + quad * 4] = w1;   // d = 16+quad*4+r
            LDS_FENCE();
            short8 ov = *(const short8*)&pw[(lane >> 2) * OSTRIDE + (lane & 3) * 8];
            unsigned short* Og = (unsigned short*)Ov;
            const size_t oidx = bbase + (size_t)(qbase + (lane >> 2)) * 32 + (lane & 3) * 8;
            *(short8*)(Og + oidx) = ov;   // wave writes 1 KiB contiguous
        } else {
            float* Og = (float*)Ov;
            const size_t ob = bbase + (size_t)(qbase + c) * 32 + quad * 4;
            #pragma unroll
            for (int r = 0; r < 4; ++r) {
                Og[ob + r]      = o0[r] * rl;
                Og[ob + 16 + r] = o1[r] * rl;
            }
        }
    }
}

extern "C" void kernel_launch(void* const* d_in, const int* in_sizes, int n_in,
                              void* d_out, int out_size, void* d_ws, size_t ws_size,
                              hipStream_t stream) {
    (void)in_sizes; (void)n_in; (void)out_size; (void)ws_size;
    const void* Qv  = d_in[0];
    const void* Kv  = d_in[1];
    const void* Vv  = d_in[2];
    const int*  VLg = (const int*)d_in[3];
    const void* Wv  = d_in[4];
    int* flags = (int*)d_ws;

    detect_kernel<<<dim3(1), dim3(256), 0, stream>>>((const unsigned short*)d_in[0], VLg, flags);
    attn_swin_kernel<false><<<dim3(1024), dim3(256), 0, stream>>>(Qv, Kv, Vv, VLg, Wv, d_out, flags);
    attn_swin_kernel<true ><<<dim3(1024), dim3(256), 0, stream>>>(Qv, Kv, Vv, VLg, Wv, d_out, flags);
}

// Round 5
// 232.381 us; speedup vs baseline: 1.1447x; 1.1447x over previous
//
#include <hip/hip_runtime.h>
#include <hip/hip_bf16.h>

// DotProductAttention (Swin windowed, masked softmax).
// Inputs are FP32 (per reference/harness; proven by rounds 1&4 bf16-only NaN
// vs rounds 2&3 dual-path pass + round-3 WRITE_SIZE=73MB ~ fp32 output).
// n=1024, Q=K=256, d=32, num_windows=64, NUM_HEADS=8.
// Block = (window w, q-tile qt, batch-quarter qr): 1024 blocks x 4 batches.
//  - mask fragment: fp32 loaded once/block, packed bf16 in 32 VGPRs
//  - K,V staged per batch into LDS as bf16 (coalesced float4 + cvt_pk);
//    V transposed so PV A-frags are ds_read_b128
//  - S^T = K*Q^T orientation: mask regs contiguous, softmax = 2 shuffles
//  - P transpose + O bounce ALIAS the dead K region (barrier after S reads)
//    -> LDS 37.4 KB -> 4 blocks/CU
//  - O via LDS bounce -> dense 2 KB/wave dwordx4 stores (fp32 out)
//  - XCD swizzle: all 16 blocks of a window on one XCD (mask/K/V L2 reuse)

typedef __attribute__((ext_vector_type(8))) short short8;   // 8 bf16 = 4 VGPR
typedef __attribute__((ext_vector_type(4))) float floatx4;  // MFMA C/D

#define KSTRIDE 40    // ushorts per K row (32 + 8 pad; 80 B, mult of 16)
#define VSTRIDE 264   // ushorts per Vt row (256 + 8 pad; 528 B, mult of 16)
#define PSTRIDE 136   // ushorts per P row (128 + 8 pad; 272 B, mult of 16)
#define OSTRIDE 36    // floats per O-bounce row (32 + 4 pad; 144 B, mult of 16)
#define NEGV -1000000.0f

#define LDS_FENCE() __asm__ volatile("s_waitcnt lgkmcnt(0)" ::: "memory")

static __device__ __forceinline__ float u2f_lo(unsigned u) {
    union { unsigned u; float f; } x; x.u = u << 16; return x.f;
}
static __device__ __forceinline__ float u2f_hi(unsigned u) {
    union { unsigned u; float f; } x; x.u = u & 0xffff0000u; return x.f;
}
static __device__ __forceinline__ unsigned packbf2(float a, float b) {
    union { __hip_bfloat162 h2; unsigned u; } x;
    x.h2 = __float22bfloat162_rn(make_float2(a, b));   // hw v_cvt_pk_bf16_f32
    return x.u;
}

union S8U { short8 s8; unsigned u[4]; };

__global__ __launch_bounds__(256, 4)
void attn_swin_kernel(const float* __restrict__ Qg,
                      const float* __restrict__ Kg,
                      const float* __restrict__ Vg,
                      const int* __restrict__ VLg,
                      const float* __restrict__ Wg,
                      float* __restrict__ Og)
{
    __shared__ __align__(16) unsigned short Ksh[256 * KSTRIDE]; // 20.0 KB (aliased: P + O bounce)
    __shared__ __align__(16) unsigned short Vt[32 * VSTRIDE];   // 16.5 KB  V^T: Vt[d][k]

    const int tid  = threadIdx.x;
    const int wave = tid >> 6;
    const int lane = tid & 63;
    const int c    = lane & 15;   // MFMA column (= q within wave's 16 rows)
    const int quad = lane >> 4;   // 0..3

    // blk -> (w, qt, qr) with all 16 blocks of window w sharing blk%8 (XCD)
    const int blk = blockIdx.x;
    const int xx  = blk & 7;
    const int yy  = blk >> 3;           // 0..127
    const int w   = xx + 8 * (yy & 7);  // 0..63
    const int zz  = yy >> 3;            // 0..15
    const int qt  = zz & 3;
    const int qr  = zz >> 2;            // 0..3
    const int b0  = (qr >> 1) * 512 + w * 8 + (qr & 1) * 4;   // 4 batches b0..b0+3
    const int qbase = qt * 64 + wave * 16;

    // valid_lens dtype probe (values in [1,256]): int64 layout => word 1 == 0
    const bool vl64 = (VLg[1] == 0);
    auto read_vl = [&](int b) -> int {
        int v = vl64 ? (int)(((const long long*)VLg)[b]) : VLg[b];
        return min(max(v, 0), 256);
    };

    // ---- window-mask fragment: fp32 load once, packed bf16 in 32 VGPRs ----
    uint2 mraw[16];
    {
        const float* wp = Wg + (size_t)w * 65536 + (size_t)(qbase + c) * 256 + quad * 4;
        #pragma unroll
        for (int t = 0; t < 16; ++t) {
            float4 m = *(const float4*)(wp + t * 16);
            mraw[t].x = packbf2(m.x, m.y);
            mraw[t].y = packbf2(m.z, m.w);
        }
    }

    const float scale = 0.17677669529663687f;  // 1/sqrt(32)
    unsigned short* const pw = &Ksh[wave * 2560];   // wave-private 5120 B alias slice

    for (int i = 0; i < 4; ++i) {
        const int b      = b0 + i;
        const int vl     = read_vl(b);
        const int used16 = (vl + 15) >> 4;
        const int used32 = (vl + 31) >> 5;
        const int tmax   = used32 * 2;
        const size_t bb  = (size_t)b * 8192;

        __syncthreads();   // A: all waves done with LDS (P/O alias, Vt) of batch i-1

        // ---- stage K (row-major) + V (transposed) as bf16; coalesced loads ----
        {
            const int r0 = tid >> 3;          // row within 32-row chunk
            const int d0 = (tid & 7) * 4;     // first of 4 d's this thread converts
            const float* kp = Kg + bb + tid * 4;
            const float* vp = Vg + bb + tid * 4;
            for (int ch = 0; ch < used32; ++ch) {
                float4 kf = *(const float4*)(kp + ch * 1024);
                float4 vf = *(const float4*)(vp + ch * 1024);
                const int row = ch * 32 + r0;
                uint2 kk;
                kk.x = packbf2(kf.x, kf.y);
                kk.y = packbf2(kf.z, kf.w);
                *(uint2*)&Ksh[row * KSTRIDE + d0] = kk;     // ds_write_b64
                unsigned v0 = packbf2(vf.x, vf.y);
                unsigned v1 = packbf2(vf.z, vf.w);
                Vt[(d0 + 0) * VSTRIDE + row] = (unsigned short)(v0 & 0xffffu);
                Vt[(d0 + 1) * VSTRIDE + row] = (unsigned short)(v0 >> 16);
                Vt[(d0 + 2) * VSTRIDE + row] = (unsigned short)(v1 & 0xffffu);
                Vt[(d0 + 3) * VSTRIDE + row] = (unsigned short)(v1 >> 16);
            }
        }
        __syncthreads();   // B: staging visible

        // ---- Q B-frag: fp32 -> packed bf16 ----
        short8 qb;
        {
            const float* qp = Qg + bb + (size_t)(qbase + c) * 32 + quad * 8;
            float4 q0 = *(const float4*)qp;
            float4 q1 = *(const float4*)(qp + 4);
            S8U t;
            t.u[0] = packbf2(q0.x, q0.y);
            t.u[1] = packbf2(q0.z, q0.w);
            t.u[2] = packbf2(q1.x, q1.y);
            t.u[3] = packbf2(q1.z, q1.w);
            qb = t.s8;
        }

        // ---- S^T = K*Q^T (A-frags from LDS) ----
        floatx4 acc[16];
        #pragma unroll
        for (int t = 0; t < 16; ++t) {
            if (t < used16) {
                short8 ka = *(const short8*)&Ksh[(t * 16 + c) * KSTRIDE + quad * 8];
                floatx4 z = {0.f, 0.f, 0.f, 0.f};
                acc[t] = __builtin_amdgcn_mfma_f32_16x16x32_bf16(ka, qb, z, 0, 0, 0);
            }
        }

        // ---- scale + register mask + valid-len; per-lane max ----
        float mx = -3.0e38f;
        #pragma unroll
        for (int t = 0; t < 16; ++t) {
            if (t < used16) {
                float m0 = u2f_lo(mraw[t].x), m1 = u2f_hi(mraw[t].x);
                float m2 = u2f_lo(mraw[t].y), m3 = u2f_hi(mraw[t].y);
                float s0 = fmaf(acc[t][0], scale, m0);
                float s1 = fmaf(acc[t][1], scale, m1);
                float s2 = fmaf(acc[t][2], scale, m2);
                float s3 = fmaf(acc[t][3], scale, m3);
                if ((t + 1) * 16 > vl) {             // boundary tile only
                    const int k0 = t * 16 + quad * 4;
                    s0 = (k0 + 0 < vl) ? s0 : NEGV;
                    s1 = (k0 + 1 < vl) ? s1 : NEGV;
                    s2 = (k0 + 2 < vl) ? s2 : NEGV;
                    s3 = (k0 + 3 < vl) ? s3 : NEGV;
                }
                acc[t][0] = s0; acc[t][1] = s1; acc[t][2] = s2; acc[t][3] = s3;
                mx = fmaxf(mx, fmaxf(fmaxf(s0, s1), fmaxf(s2, s3)));
            }
        }
        mx = fmaxf(mx, __shfl_xor(mx, 16));
        mx = fmaxf(mx, __shfl_xor(mx, 32));

        // ---- exp + sum; pack P to bf16 pairs ----
        float l = 0.f;
        uint2 pk[16];
        #pragma unroll
        for (int t = 0; t < 16; ++t) {
            if (t < used16) {
                float p0 = __expf(acc[t][0] - mx);
                float p1 = __expf(acc[t][1] - mx);
                float p2 = __expf(acc[t][2] - mx);
                float p3 = __expf(acc[t][3] - mx);
                l += (p0 + p1) + (p2 + p3);
                pk[t].x = packbf2(p0, p1);
                pk[t].y = packbf2(p2, p3);
            } else if (t < tmax) {
                pk[t].x = 0u; pk[t].y = 0u;
            }
        }
        l += __shfl_xor(l, 16);
        l += __shfl_xor(l, 32);
        const float rl = (l > 0.f) ? (1.0f / l) : 0.f;

        __syncthreads();   // C: all waves done reading Ksh -> safe to alias with P/O

        // ---- PV in two k-halves through wave-private alias slice ----
        floatx4 o0 = {0.f, 0.f, 0.f, 0.f}, o1 = {0.f, 0.f, 0.f, 0.f};

        #pragma unroll
        for (int t = 0; t < 8; ++t) {
            if (t < tmax)
                *(uint2*)&pw[c * PSTRIDE + t * 16 + quad * 4] = pk[t];
        }
        LDS_FENCE();
        #pragma unroll
        for (int kt = 0; kt < 4; ++kt) {
            if (kt < used32) {
                short8 pb  = *(const short8*)&pw[c * PSTRIDE + kt * 32 + quad * 8];
                short8 va0 = *(const short8*)&Vt[c * VSTRIDE + kt * 32 + quad * 8];
                short8 va1 = *(const short8*)&Vt[(16 + c) * VSTRIDE + kt * 32 + quad * 8];
                o0 = __builtin_amdgcn_mfma_f32_16x16x32_bf16(va0, pb, o0, 0, 0, 0);
                o1 = __builtin_amdgcn_mfma_f32_16x16x32_bf16(va1, pb, o1, 0, 0, 0);
            }
        }
        if (used32 > 4) {
            #pragma unroll
            for (int t = 8; t < 16; ++t) {
                if (t < tmax)
                    *(uint2*)&pw[c * PSTRIDE + (t - 8) * 16 + quad * 4] = pk[t];
            }
            LDS_FENCE();
            #pragma unroll
            for (int kt = 4; kt < 8; ++kt) {
                if (kt < used32) {
                    short8 pb  = *(const short8*)&pw[c * PSTRIDE + (kt - 4) * 32 + quad * 8];
                    short8 va0 = *(const short8*)&Vt[c * VSTRIDE + kt * 32 + quad * 8];
                    short8 va1 = *(const short8*)&Vt[(16 + c) * VSTRIDE + kt * 32 + quad * 8];
                    o0 = __builtin_amdgcn_mfma_f32_16x16x32_bf16(va0, pb, o0, 0, 0, 0);
                    o1 = __builtin_amdgcn_mfma_f32_16x16x32_bf16(va1, pb, o1, 0, 0, 0);
                }
            }
        }

        // ---- normalize; bounce O through alias slice -> dense fp32 stores ----
        {
            float* ow = (float*)pw;   // stride OSTRIDE floats
            LDS_FENCE();              // compiler fence: P reads before O writes
            float4 w0, w1;
            w0.x = o0[0] * rl; w0.y = o0[1] * rl; w0.z = o0[2] * rl; w0.w = o0[3] * rl;
            w1.x = o1[0] * rl; w1.y = o1[1] * rl; w1.z = o1[2] * rl; w1.w = o1[3] * rl;
            *(float4*)&ow[c * OSTRIDE + quad * 4]      = w0;   // d = quad*4..+3
            *(float4*)&ow[c * OSTRIDE + 16 + quad * 4] = w1;   // d = 16+quad*4..+3
            LDS_FENCE();              // O writes visible before reads
            const int qq = lane >> 2, seg = lane & 3;
            float4 r0 = *(const float4*)&ow[qq * OSTRIDE + seg * 8];
            float4 r1 = *(const float4*)&ow[qq * OSTRIDE + seg * 8 + 4];
            float* op = Og + bb + (size_t)(qbase + qq) * 32 + seg * 8;
            *(float4*)op       = r0;   // wave covers 2 KiB dense
            *(float4*)(op + 4) = r1;
        }
    }
}

extern "C" void kernel_launch(void* const* d_in, const int* in_sizes, int n_in,
                              void* d_out, int out_size, void* d_ws, size_t ws_size,
                              hipStream_t stream) {
    (void)in_sizes; (void)n_in; (void)out_size; (void)d_ws; (void)ws_size;
    const float* Qg  = (const float*)d_in[0];
    const float* Kg  = (const float*)d_in[1];
    const float* Vg  = (const float*)d_in[2];
    const int*   VLg = (const int*)d_in[3];
    const float* Wg  = (const float*)d_in[4];
    float*       Og  = (float*)d_out;

    attn_swin_kernel<<<dim3(1024), dim3(256), 0, stream>>>(Qg, Kg, Vg, VLg, Wg, Og);
}